// Round 15
// baseline (911.829 us; speedup 1.0000x reference)
//
#include <hip/hip_runtime.h>

typedef unsigned short ushort_t;
typedef unsigned int uint_t;

typedef __attribute__((ext_vector_type(8))) __bf16 bf16x8_t;
typedef __attribute__((ext_vector_type(8))) short s16x8;
typedef __attribute__((ext_vector_type(4))) float f32x4;

#define T_TOK 2048
#define H_DIM 2048
#define I_DIM 1024
#define N_EXP 64
#define TOPK 8
#define MT 6         // 128-row m-tiles: covers up to 768 tokens/expert (mean 256)
#define LSTR 40      // LDS row stride in bf16 elems (BK=32 + 8 pad) — R4-proven

// Raw barrier: does NOT drain vmcnt -> in-flight global loads stay outstanding.
#define BAR_RAW()  asm volatile("s_barrier" ::: "memory")
// LDS-visibility barrier: drain ds ops (lgkm) then barrier; vmcnt untouched.
#define BAR_LGKM() asm volatile("s_waitcnt lgkmcnt(0)\n\ts_barrier" ::: "memory")

__device__ inline f32x4 mfma_bf16(s16x8 a, s16x8 b, f32x4 c) {
  return __builtin_amdgcn_mfma_f32_16x16x32_bf16(
      __builtin_bit_cast(bf16x8_t, a), __builtin_bit_cast(bf16x8_t, b), c, 0, 0, 0);
}

__device__ inline ushort_t f2bf(float f) {
  uint_t u = __float_as_uint(f);
  u += 0x7FFFu + ((u >> 16) & 1u);   // round-to-nearest-even
  return (ushort_t)(u >> 16);
}

// packed f32x2 -> bf16x2 (RNE), 1 instruction
__device__ inline uint_t pkbf(float a, float b) {
  uint_t r;
  asm("v_cvt_pk_bf16_f32 %0, %1, %2" : "=v"(r) : "v"(a), "v"(b));
  return r;
}
// float4 -> 4 bf16 (8 B)
__device__ inline uint2 pk4(float4 v) {
  uint2 w;
  w.x = pkbf(v.x, v.y);
  w.y = pkbf(v.z, v.w);
  return w;
}

// XCD-chunk swizzle (bijective when nwg % 8 == 0): each XCD gets a contiguous
// logical-bid chunk; with mt-fastest decomposition, the MT readers of a weight
// panel are consecutive logical bids -> same XCD -> panel re-reads are L2-local.
__device__ __forceinline__ int xcd_swizzle(int bid, int nwg) {
  int q = nwg >> 3;
  return (bid & 7) * q + (bid >> 3);
}

// ---------------- Router: logits[t][e] = sum_h x[t][h] * gw[e][h] (fp32 exact) ----------
__global__ __launch_bounds__(256) void router_kernel(const float* __restrict__ X,
                                                     const float* __restrict__ GW,
                                                     float* __restrict__ logits) {
  __shared__ float xs[4][H_DIM];
  int tid = threadIdx.x;
  int t0 = blockIdx.x * 4;
  const float4* src = (const float4*)(X + (size_t)t0 * H_DIM);
  float4* dst = (float4*)(&xs[0][0]);
#pragma unroll
  for (int j = 0; j < 8; ++j) dst[tid + 256 * j] = src[tid + 256 * j];
  __syncthreads();
  int wave = tid >> 6, lane = tid & 63;
  int t = t0 + wave;
  const float4* w = (const float4*)(GW + (size_t)lane * H_DIM);
  const float4* xr = (const float4*)(&xs[wave][0]);
  float acc = 0.f;
  for (int i = 0; i < H_DIM / 4; ++i) {
    float4 a = xr[i];
    float4 b = w[i];
    acc = fmaf(a.x, b.x, acc);
    acc = fmaf(a.y, b.y, acc);
    acc = fmaf(a.z, b.z, acc);
    acc = fmaf(a.w, b.w, acc);
  }
  logits[(size_t)t * N_EXP + lane] = acc;
}

// ---------------- Softmax + top-8 per token (one wave per token) -----------------------
__global__ __launch_bounds__(256) void topk_kernel(const float* __restrict__ logits,
                                                   int* __restrict__ counts,
                                                   int* __restrict__ sel_e,
                                                   float* __restrict__ sel_w) {
  int tid = threadIdx.x;
  int wave = tid >> 6, lane = tid & 63;
  int t = blockIdx.x * 4 + wave;
  float l = logits[(size_t)t * N_EXP + lane];
  float m = l;
#pragma unroll
  for (int s = 32; s; s >>= 1) m = fmaxf(m, __shfl_xor(m, s, 64));
  float p = __expf(l - m);
  float sum = p;
#pragma unroll
  for (int s = 32; s; s >>= 1) sum += __shfl_xor(sum, s, 64);
  float prob = p / sum;

  float val = l;
#pragma unroll
  for (int k = 0; k < TOPK; ++k) {
    float bv = val;
    int bi = lane;
#pragma unroll
    for (int s = 32; s; s >>= 1) {
      float ov = __shfl_xor(bv, s, 64);
      int oi = __shfl_xor(bi, s, 64);
      if (ov > bv || (ov == bv && oi < bi)) { bv = ov; bi = oi; }
    }
    float bw = __shfl(prob, bi, 64);
    if (lane == 0) {
      sel_e[t * TOPK + k] = bi;
      sel_w[t * TOPK + k] = bw;
      atomicAdd(&counts[bi], 1);
    }
    if (lane == bi) val = -INFINITY;
  }
}

// ---------------- Prefix sum over 64 expert counts -------------------------------------
__global__ void scan_kernel(const int* __restrict__ counts, int* __restrict__ offsets,
                            int* __restrict__ cursor) {
  if (threadIdx.x == 0) {
    int acc = 0;
    for (int e = 0; e < N_EXP; ++e) { offsets[e] = acc; acc += counts[e]; }
    offsets[N_EXP] = acc;
  }
  if (threadIdx.x < N_EXP) cursor[threadIdx.x] = 0;
}

// ---------------- Assign packed rows ---------------------------------------------------
__global__ __launch_bounds__(256) void assign_kernel(const int* __restrict__ sel_e,
                                                     const float* __restrict__ sel_w,
                                                     const int* __restrict__ offsets,
                                                     int* __restrict__ cursor,
                                                     int* __restrict__ token_of,
                                                     float* __restrict__ weight_of) {
  int idx = blockIdx.x * 256 + threadIdx.x;  // 0..16383
  int t = idx >> 3;
  int e = sel_e[idx];
  float w = sel_w[idx];
  int r = offsets[e] + atomicAdd(&cursor[e], 1);
  token_of[r] = t;
  weight_of[r] = w;
}

// ---------------- Fused gate+up GEMM + SiLU -> act (bf16) ------------------------------
// R10 base (series best): 512 thr, block tile 128(M)x128(N) x2 projections, BK=32,
// 8 waves (2M x 4N), wave tile 64x32/projection (acc = 16 f32x4), 1-deep register
// prefetch, 2-barrier schedule, (512,3) no-spill. ONLY change vs R10: mt-fastest
// bid order (R14-proven: FETCH 0.95 -> 0.63 GB).
__global__ __launch_bounds__(512, 3) void gateup_kernel(const float* __restrict__ X,
                                                        const float* __restrict__ Wg,
                                                        const float* __restrict__ Wu,
                                                        const int* __restrict__ offsets,
                                                        const int* __restrict__ token_of,
                                                        ushort_t* __restrict__ act) {
  int bid = xcd_swizzle(blockIdx.x, N_EXP * MT * 8);
  int e = bid / (MT * 8);
  int rem = bid % (MT * 8);
  int nt = rem / MT;       // mt fastest: consecutive bids share the (e,nt) panel
  int mt = rem % MT;
  int base = offsets[e];
  int Me = offsets[e + 1] - base;
  if (mt * 128 >= Me) return;

  __shared__ ushort_t As[128 * LSTR];   // 10 KB
  __shared__ ushort_t Bgs[128 * LSTR];  // 10 KB
  __shared__ ushort_t Bus[128 * LSTR];  // 10 KB
  __shared__ int stok[128];

  int tid = threadIdx.x;
  if (tid < 128) {
    int gm = mt * 128 + tid;
    int cm = gm < Me ? gm : (Me - 1);
    stok[tid] = token_of[base + cm];
  }
  __syncthreads();

  int wave = tid >> 6, lane = tid & 63;
  int wm = wave >> 2, wn = wave & 3;

  // Staging: 4 thr/row x 128 rows; each thread 8 floats (2 float4) at col (tid&3)*8.
  // One wave instruction = 16 rows x 128 B contiguous runs.
  int sr = tid >> 2, sc = (tid & 3) * 8;
  const float* pA = X + (size_t)stok[sr] * H_DIM + sc;
  const float* pG = Wg + ((size_t)e * I_DIM + nt * 128 + sr) * H_DIM + sc;
  const float* pU = Wu + ((size_t)e * I_DIM + nt * 128 + sr) * H_DIM + sc;

  f32x4 accg[4][2], accu[4][2];
#pragma unroll
  for (int i = 0; i < 4; ++i)
#pragma unroll
    for (int j = 0; j < 2; ++j) { accg[i][j] = (f32x4)0.f; accu[i][j] = (f32x4)0.f; }

  float4 rA[2], rG[2], rU[2];
  // prologue: tile 0 -> regs
#pragma unroll
  for (int j = 0; j < 2; ++j) {
    rA[j] = *(const float4*)(pA + 4 * j);
    rG[j] = *(const float4*)(pG + 4 * j);
    rU[j] = *(const float4*)(pU + 4 * j);
  }

  int fr = lane & 15, q2 = lane >> 4;

  for (int k0 = 0; k0 < H_DIM; k0 += 32) {
    BAR_RAW();  // all waves done reading prev tile; prefetch loads cross freely
    *(uint2*)&As[sr * LSTR + sc] = pk4(rA[0]);
    *(uint2*)&As[sr * LSTR + sc + 4] = pk4(rA[1]);
    *(uint2*)&Bgs[sr * LSTR + sc] = pk4(rG[0]);
    *(uint2*)&Bgs[sr * LSTR + sc + 4] = pk4(rG[1]);
    *(uint2*)&Bus[sr * LSTR + sc] = pk4(rU[0]);
    *(uint2*)&Bus[sr * LSTR + sc + 4] = pk4(rU[1]);
    if (k0 + 32 < H_DIM) {
      int kn = k0 + 32;
#pragma unroll
      for (int j = 0; j < 2; ++j) {
        rA[j] = *(const float4*)(pA + kn + 4 * j);
        rG[j] = *(const float4*)(pG + kn + 4 * j);
        rU[j] = *(const float4*)(pU + kn + 4 * j);
      }
    }
    BAR_LGKM();  // ds_writes visible; vmcnt untouched (prefetch in flight)

    s16x8 af[4], bg[2], bu[2];
#pragma unroll
    for (int mf = 0; mf < 4; ++mf)
      af[mf] = *(const s16x8*)&As[(wm * 64 + mf * 16 + fr) * LSTR + q2 * 8];
#pragma unroll
    for (int nf = 0; nf < 2; ++nf) {
      bg[nf] = *(const s16x8*)&Bgs[(wn * 32 + nf * 16 + fr) * LSTR + q2 * 8];
      bu[nf] = *(const s16x8*)&Bus[(wn * 32 + nf * 16 + fr) * LSTR + q2 * 8];
    }
    __builtin_amdgcn_s_setprio(1);
#pragma unroll
    for (int mf = 0; mf < 4; ++mf)
#pragma unroll
      for (int nf = 0; nf < 2; ++nf) {
        accg[mf][nf] = mfma_bf16(af[mf], bg[nf], accg[mf][nf]);
        accu[mf][nf] = mfma_bf16(af[mf], bu[nf], accu[mf][nf]);
      }
    __builtin_amdgcn_s_setprio(0);
  }

  // epilogue: act = silu(g)*u -> bf16
#pragma unroll
  for (int mf = 0; mf < 4; ++mf)
#pragma unroll
    for (int nf = 0; nf < 2; ++nf) {
      f32x4 g = accg[mf][nf], u = accu[mf][nf];
#pragma unroll
      for (int r = 0; r < 4; ++r) {
        int mloc = wm * 64 + mf * 16 + q2 * 4 + r;
        int gm = mt * 128 + mloc;
        if (gm < Me) {
          float gv = g[r], uv = u[r];
          float s = gv / (1.f + __expf(-gv));
          int col = nt * 128 + wn * 32 + nf * 16 + fr;
          act[(size_t)(base + gm) * I_DIM + col] = f2bf(s * uv);
        }
      }
    }
}

// ---------------- Down GEMM + weighted scatter to out ----------------------------------
// R10 base: 512 thr, tile 128x128, BK=32, 8 waves (2Mx4N), acc = 8 f32x4, (512,4),
// 1-deep prefetch. ONLY change vs R10: mt-fastest bid order.
__global__ __launch_bounds__(512, 4) void down_kernel(const ushort_t* __restrict__ act,
                                                      const float* __restrict__ Wd,
                                                      const int* __restrict__ offsets,
                                                      const int* __restrict__ token_of,
                                                      const float* __restrict__ weight_of,
                                                      float* __restrict__ out) {
  int bid = xcd_swizzle(blockIdx.x, N_EXP * MT * 16);
  int e = bid / (MT * 16);
  int rem = bid % (MT * 16);
  int nt = rem / MT;       // mt fastest
  int mt = rem % MT;
  int base = offsets[e];
  int Me = offsets[e + 1] - base;
  if (mt * 128 >= Me) return;

  __shared__ ushort_t As[128 * LSTR];   // 10 KB
  __shared__ ushort_t Bs[128 * LSTR];   // 10 KB
  __shared__ int stok[128];
  __shared__ float sw[128];

  int tid = threadIdx.x;
  if (tid < 128) {
    int gm = mt * 128 + tid;
    int ok = gm < Me;
    int cm = ok ? gm : (Me - 1);
    stok[tid] = token_of[base + cm];
    sw[tid] = ok ? weight_of[base + gm] : 0.f;
  }
  __syncthreads();

  int wave = tid >> 6, lane = tid & 63;
  int wm = wave >> 2, wn = wave & 3;

  // A (act, bf16): 4 thr/row x 128 rows, 16 B each -> 16 rows x 64 B runs per wave instr
  int sr = tid >> 2;
  int ac = (tid & 3) * 8;     // bf16 col
  int r0 = mt * 128 + sr;
  if (r0 >= Me) r0 = Me - 1;
  const ushort_t* pA = act + (size_t)(base + r0) * I_DIM + ac;
  // B (Wd, fp32): 4 thr/row x 128 rows, each 8 floats -> 16 rows x 128 B runs
  int bc = (tid & 3) * 8;
  const float* pB = Wd + ((size_t)e * H_DIM + nt * 128 + sr) * I_DIM + bc;

  f32x4 acc[4][2];
#pragma unroll
  for (int i = 0; i < 4; ++i)
#pragma unroll
    for (int j = 0; j < 2; ++j) acc[i][j] = (f32x4)0.f;

  s16x8 rA;
  float4 rB[2];
  rA = *(const s16x8*)pA;
#pragma unroll
  for (int j = 0; j < 2; ++j) rB[j] = *(const float4*)(pB + 4 * j);

  int fr = lane & 15, q2 = lane >> 4;

  for (int k0 = 0; k0 < I_DIM; k0 += 32) {
    BAR_RAW();
    *(s16x8*)&As[sr * LSTR + ac] = rA;
    *(uint2*)&Bs[sr * LSTR + bc] = pk4(rB[0]);
    *(uint2*)&Bs[sr * LSTR + bc + 4] = pk4(rB[1]);
    if (k0 + 32 < I_DIM) {
      int kn = k0 + 32;
      rA = *(const s16x8*)(pA + kn);
#pragma unroll
      for (int j = 0; j < 2; ++j) rB[j] = *(const float4*)(pB + kn + 4 * j);
    }
    BAR_LGKM();

    s16x8 af[4], bf[2];
#pragma unroll
    for (int mf = 0; mf < 4; ++mf)
      af[mf] = *(const s16x8*)&As[(wm * 64 + mf * 16 + fr) * LSTR + q2 * 8];
#pragma unroll
    for (int nf = 0; nf < 2; ++nf)
      bf[nf] = *(const s16x8*)&Bs[(wn * 32 + nf * 16 + fr) * LSTR + q2 * 8];
    __builtin_amdgcn_s_setprio(1);
#pragma unroll
    for (int mf = 0; mf < 4; ++mf)
#pragma unroll
      for (int nf = 0; nf < 2; ++nf)
        acc[mf][nf] = mfma_bf16(af[mf], bf[nf], acc[mf][nf]);
    __builtin_amdgcn_s_setprio(0);
  }

#pragma unroll
  for (int mf = 0; mf < 4; ++mf)
#pragma unroll
    for (int nf = 0; nf < 2; ++nf) {
      f32x4 v = acc[mf][nf];
#pragma unroll
      for (int r = 0; r < 4; ++r) {
        int mloc = wm * 64 + mf * 16 + q2 * 4 + r;
        int gm = mt * 128 + mloc;
        if (gm < Me) {
          int t = stok[mloc];
          float w = sw[mloc];
          int h = nt * 128 + wn * 32 + nf * 16 + fr;
          unsafeAtomicAdd(&out[(size_t)t * H_DIM + h], w * v[r]);
        }
      }
    }
}

// ---------------------------------------------------------------------------------------
extern "C" void kernel_launch(void* const* d_in, const int* in_sizes, int n_in,
                              void* d_out, int out_size, void* d_ws, size_t ws_size,
                              hipStream_t stream) {
  const float* X = (const float*)d_in[0];
  const float* GW = (const float*)d_in[1];
  const float* Wg = (const float*)d_in[2];
  const float* Wu = (const float*)d_in[3];
  const float* Wd = (const float*)d_in[4];
  float* out = (float*)d_out;
  float* logits = out + (size_t)T_TOK * H_DIM;

  char* ws = (char*)d_ws;
  int* counts = (int*)ws;                       // 256 B
  int* cursor = (int*)(ws + 256);               // 256 B
  int* offsets = (int*)(ws + 512);              // 260 B
  int* sel_e = (int*)(ws + 1024);               // 64 KB
  float* sel_w = (float*)(ws + 1024 + 65536);   // 64 KB
  int* token_of = (int*)(ws + 1024 + 2 * 65536);
  float* weight_of = (float*)(ws + 1024 + 3 * 65536);
  ushort_t* act = (ushort_t*)(ws + 524288);     // 16384*1024*2 = 32 MB

  hipMemsetAsync(out, 0, (size_t)T_TOK * H_DIM * sizeof(float), stream);
  hipMemsetAsync(ws, 0, 1024, stream);

  router_kernel<<<T_TOK / 4, 256, 0, stream>>>(X, GW, logits);
  topk_kernel<<<T_TOK / 4, 256, 0, stream>>>(logits, counts, sel_e, sel_w);
  scan_kernel<<<1, 64, 0, stream>>>(counts, offsets, cursor);
  assign_kernel<<<(T_TOK * TOPK) / 256, 256, 0, stream>>>(sel_e, sel_w, offsets, cursor,
                                                          token_of, weight_of);
  gateup_kernel<<<N_EXP * MT * 8, 512, 0, stream>>>(X, Wg, Wu, offsets, token_of, act);
  down_kernel<<<N_EXP * MT * 16, 512, 0, stream>>>(act, Wd, offsets, token_of,
                                                   weight_of, out);
}

// Round 16
// 836.767 us; speedup vs baseline: 1.0897x; 1.0897x over previous
//
#include <hip/hip_runtime.h>

typedef unsigned short ushort_t;
typedef unsigned int uint_t;

typedef __attribute__((ext_vector_type(8))) __bf16 bf16x8_t;
typedef __attribute__((ext_vector_type(8))) short s16x8;
typedef __attribute__((ext_vector_type(4))) float f32x4;

#define T_TOK 2048
#define H_DIM 2048
#define I_DIM 1024
#define N_EXP 64
#define TOPK 8
#define MT 6         // 128-row m-tiles: covers up to 768 tokens/expert (mean 256)
#define LSTR 40      // LDS row stride in bf16 elems (BK=32 + 8 pad) — R4-proven

// Raw barrier: does NOT drain vmcnt -> in-flight global loads stay outstanding.
#define BAR_RAW()  asm volatile("s_barrier" ::: "memory")
// LDS-visibility barrier: drain ds ops (lgkm) then barrier; vmcnt untouched.
#define BAR_LGKM() asm volatile("s_waitcnt lgkmcnt(0)\n\ts_barrier" ::: "memory")

__device__ inline f32x4 mfma_bf16(s16x8 a, s16x8 b, f32x4 c) {
  return __builtin_amdgcn_mfma_f32_16x16x32_bf16(
      __builtin_bit_cast(bf16x8_t, a), __builtin_bit_cast(bf16x8_t, b), c, 0, 0, 0);
}

__device__ inline ushort_t f2bf(float f) {
  uint_t u = __float_as_uint(f);
  u += 0x7FFFu + ((u >> 16) & 1u);   // round-to-nearest-even
  return (ushort_t)(u >> 16);
}

// packed f32x2 -> bf16x2 (RNE), 1 instruction
__device__ inline uint_t pkbf(float a, float b) {
  uint_t r;
  asm("v_cvt_pk_bf16_f32 %0, %1, %2" : "=v"(r) : "v"(a), "v"(b));
  return r;
}
// float4 -> 4 bf16 (8 B)
__device__ inline uint2 pk4(float4 v) {
  uint2 w;
  w.x = pkbf(v.x, v.y);
  w.y = pkbf(v.z, v.w);
  return w;
}

// XCD-chunk swizzle (bijective when nwg % 8 == 0)
__device__ __forceinline__ int xcd_swizzle(int bid, int nwg) {
  int q = nwg >> 3;
  return (bid & 7) * q + (bid >> 3);
}

// ---------------- Router: logits[t][e] = sum_h x[t][h] * gw[e][h] (fp32 exact) ----------
__global__ __launch_bounds__(256) void router_kernel(const float* __restrict__ X,
                                                     const float* __restrict__ GW,
                                                     float* __restrict__ logits) {
  __shared__ float xs[4][H_DIM];
  int tid = threadIdx.x;
  int t0 = blockIdx.x * 4;
  const float4* src = (const float4*)(X + (size_t)t0 * H_DIM);
  float4* dst = (float4*)(&xs[0][0]);
#pragma unroll
  for (int j = 0; j < 8; ++j) dst[tid + 256 * j] = src[tid + 256 * j];
  __syncthreads();
  int wave = tid >> 6, lane = tid & 63;
  int t = t0 + wave;
  const float4* w = (const float4*)(GW + (size_t)lane * H_DIM);
  const float4* xr = (const float4*)(&xs[wave][0]);
  float acc = 0.f;
  for (int i = 0; i < H_DIM / 4; ++i) {
    float4 a = xr[i];
    float4 b = w[i];
    acc = fmaf(a.x, b.x, acc);
    acc = fmaf(a.y, b.y, acc);
    acc = fmaf(a.z, b.z, acc);
    acc = fmaf(a.w, b.w, acc);
  }
  logits[(size_t)t * N_EXP + lane] = acc;
}

// ---------------- Softmax + top-8 per token (one wave per token) -----------------------
__global__ __launch_bounds__(256) void topk_kernel(const float* __restrict__ logits,
                                                   int* __restrict__ counts,
                                                   int* __restrict__ sel_e,
                                                   float* __restrict__ sel_w) {
  int tid = threadIdx.x;
  int wave = tid >> 6, lane = tid & 63;
  int t = blockIdx.x * 4 + wave;
  float l = logits[(size_t)t * N_EXP + lane];
  float m = l;
#pragma unroll
  for (int s = 32; s; s >>= 1) m = fmaxf(m, __shfl_xor(m, s, 64));
  float p = __expf(l - m);
  float sum = p;
#pragma unroll
  for (int s = 32; s; s >>= 1) sum += __shfl_xor(sum, s, 64);
  float prob = p / sum;

  float val = l;
#pragma unroll
  for (int k = 0; k < TOPK; ++k) {
    float bv = val;
    int bi = lane;
#pragma unroll
    for (int s = 32; s; s >>= 1) {
      float ov = __shfl_xor(bv, s, 64);
      int oi = __shfl_xor(bi, s, 64);
      if (ov > bv || (ov == bv && oi < bi)) { bv = ov; bi = oi; }
    }
    float bw = __shfl(prob, bi, 64);
    if (lane == 0) {
      sel_e[t * TOPK + k] = bi;
      sel_w[t * TOPK + k] = bw;
      atomicAdd(&counts[bi], 1);
    }
    if (lane == bi) val = -INFINITY;
  }
}

// ---------------- Prefix sum over 64 expert counts -------------------------------------
__global__ void scan_kernel(const int* __restrict__ counts, int* __restrict__ offsets,
                            int* __restrict__ cursor) {
  if (threadIdx.x == 0) {
    int acc = 0;
    for (int e = 0; e < N_EXP; ++e) { offsets[e] = acc; acc += counts[e]; }
    offsets[N_EXP] = acc;
  }
  if (threadIdx.x < N_EXP) cursor[threadIdx.x] = 0;
}

// ---------------- Assign packed rows ---------------------------------------------------
__global__ __launch_bounds__(256) void assign_kernel(const int* __restrict__ sel_e,
                                                     const float* __restrict__ sel_w,
                                                     const int* __restrict__ offsets,
                                                     int* __restrict__ cursor,
                                                     int* __restrict__ token_of,
                                                     float* __restrict__ weight_of) {
  int idx = blockIdx.x * 256 + threadIdx.x;  // 0..16383
  int t = idx >> 3;
  int e = sel_e[idx];
  float w = sel_w[idx];
  int r = offsets[e] + atomicAdd(&cursor[e], 1);
  token_of[r] = t;
  weight_of[r] = w;
}

// ---------------- Fused gate+up GEMM + SiLU -> act (bf16) ------------------------------
// R10 base (series best, nt-fastest ordering) + 2-deep register prefetch
// (R14-vs-R15 isolated: -6%). 512 thr, tile 128(M)x128(N) x2 proj, BK=32,
// 8 waves (2M x 4N), wave tile 64x32/proj (acc = 16 f32x4), (512,3) no-spill.
__global__ __launch_bounds__(512, 3) void gateup_kernel(const float* __restrict__ X,
                                                        const float* __restrict__ Wg,
                                                        const float* __restrict__ Wu,
                                                        const int* __restrict__ offsets,
                                                        const int* __restrict__ token_of,
                                                        ushort_t* __restrict__ act) {
  int bid = xcd_swizzle(blockIdx.x, N_EXP * MT * 8);
  int e = bid / (MT * 8);
  int mt = (bid % (MT * 8)) / 8;   // nt fastest (R10 ordering)
  int nt = bid % 8;
  int base = offsets[e];
  int Me = offsets[e + 1] - base;
  if (mt * 128 >= Me) return;

  __shared__ ushort_t As[128 * LSTR];   // 10 KB
  __shared__ ushort_t Bgs[128 * LSTR];  // 10 KB
  __shared__ ushort_t Bus[128 * LSTR];  // 10 KB
  __shared__ int stok[128];

  int tid = threadIdx.x;
  if (tid < 128) {
    int gm = mt * 128 + tid;
    int cm = gm < Me ? gm : (Me - 1);
    stok[tid] = token_of[base + cm];
  }
  __syncthreads();

  int wave = tid >> 6, lane = tid & 63;
  int wm = wave >> 2, wn = wave & 3;

  // Staging: 4 thr/row x 128 rows; each thread 8 floats (2 float4) at col (tid&3)*8.
  int sr = tid >> 2, sc = (tid & 3) * 8;
  const float* pA = X + (size_t)stok[sr] * H_DIM + sc;
  const float* pG = Wg + ((size_t)e * I_DIM + nt * 128 + sr) * H_DIM + sc;
  const float* pU = Wu + ((size_t)e * I_DIM + nt * 128 + sr) * H_DIM + sc;

  f32x4 accg[4][2], accu[4][2];
#pragma unroll
  for (int i = 0; i < 4; ++i)
#pragma unroll
    for (int j = 0; j < 2; ++j) { accg[i][j] = (f32x4)0.f; accu[i][j] = (f32x4)0.f; }

  // two prefetch sets: set0 = even tiles, set1 = odd tiles (2-deep)
  float4 a0[2], g0[2], u0[2], a1[2], g1[2], u1[2];
#pragma unroll
  for (int j = 0; j < 2; ++j) {
    a0[j] = *(const float4*)(pA + 4 * j);
    g0[j] = *(const float4*)(pG + 4 * j);
    u0[j] = *(const float4*)(pU + 4 * j);
    a1[j] = *(const float4*)(pA + 32 + 4 * j);
    g1[j] = *(const float4*)(pG + 32 + 4 * j);
    u1[j] = *(const float4*)(pU + 32 + 4 * j);
  }

  int fr = lane & 15, q2 = lane >> 4;
  const int NK = H_DIM / 32;  // 64 (even)

#define GU_COMPUTE()                                                                \
  {                                                                                 \
    s16x8 af[4], bg[2], bu[2];                                                      \
    _Pragma("unroll")                                                               \
    for (int mf = 0; mf < 4; ++mf)                                                  \
      af[mf] = *(const s16x8*)&As[(wm * 64 + mf * 16 + fr) * LSTR + q2 * 8];        \
    _Pragma("unroll")                                                               \
    for (int nf = 0; nf < 2; ++nf) {                                                \
      bg[nf] = *(const s16x8*)&Bgs[(wn * 32 + nf * 16 + fr) * LSTR + q2 * 8];       \
      bu[nf] = *(const s16x8*)&Bus[(wn * 32 + nf * 16 + fr) * LSTR + q2 * 8];       \
    }                                                                               \
    __builtin_amdgcn_s_setprio(1);                                                  \
    _Pragma("unroll")                                                               \
    for (int mf = 0; mf < 4; ++mf)                                                  \
      _Pragma("unroll")                                                             \
      for (int nf = 0; nf < 2; ++nf) {                                              \
        accg[mf][nf] = mfma_bf16(af[mf], bg[nf], accg[mf][nf]);                     \
        accu[mf][nf] = mfma_bf16(af[mf], bu[nf], accu[mf][nf]);                     \
      }                                                                             \
    __builtin_amdgcn_s_setprio(0);                                                  \
  }

  for (int k = 0; k < NK; k += 2) {
    // ---- even tile k (set0); ds_write's vmcnt wait targets loads from iter k-2 ----
    BAR_RAW();
    *(uint2*)&As[sr * LSTR + sc] = pk4(a0[0]);
    *(uint2*)&As[sr * LSTR + sc + 4] = pk4(a0[1]);
    *(uint2*)&Bgs[sr * LSTR + sc] = pk4(g0[0]);
    *(uint2*)&Bgs[sr * LSTR + sc + 4] = pk4(g0[1]);
    *(uint2*)&Bus[sr * LSTR + sc] = pk4(u0[0]);
    *(uint2*)&Bus[sr * LSTR + sc + 4] = pk4(u0[1]);
    if (k + 2 < NK) {
      int kn = (k + 2) * 32;
#pragma unroll
      for (int j = 0; j < 2; ++j) {
        a0[j] = *(const float4*)(pA + kn + 4 * j);
        g0[j] = *(const float4*)(pG + kn + 4 * j);
        u0[j] = *(const float4*)(pU + kn + 4 * j);
      }
    }
    BAR_LGKM();
    GU_COMPUTE();

    // ---- odd tile k+1 (set1) ----
    BAR_RAW();
    *(uint2*)&As[sr * LSTR + sc] = pk4(a1[0]);
    *(uint2*)&As[sr * LSTR + sc + 4] = pk4(a1[1]);
    *(uint2*)&Bgs[sr * LSTR + sc] = pk4(g1[0]);
    *(uint2*)&Bgs[sr * LSTR + sc + 4] = pk4(g1[1]);
    *(uint2*)&Bus[sr * LSTR + sc] = pk4(u1[0]);
    *(uint2*)&Bus[sr * LSTR + sc + 4] = pk4(u1[1]);
    if (k + 3 < NK) {
      int kn = (k + 3) * 32;
#pragma unroll
      for (int j = 0; j < 2; ++j) {
        a1[j] = *(const float4*)(pA + kn + 4 * j);
        g1[j] = *(const float4*)(pG + kn + 4 * j);
        u1[j] = *(const float4*)(pU + kn + 4 * j);
      }
    }
    BAR_LGKM();
    GU_COMPUTE();
  }

  // epilogue: act = silu(g)*u -> bf16
#pragma unroll
  for (int mf = 0; mf < 4; ++mf)
#pragma unroll
    for (int nf = 0; nf < 2; ++nf) {
      f32x4 g = accg[mf][nf], u = accu[mf][nf];
#pragma unroll
      for (int r = 0; r < 4; ++r) {
        int mloc = wm * 64 + mf * 16 + q2 * 4 + r;
        int gm = mt * 128 + mloc;
        if (gm < Me) {
          float gv = g[r], uv = u[r];
          float s = gv / (1.f + __expf(-gv));
          int col = nt * 128 + wn * 32 + nf * 16 + fr;
          act[(size_t)(base + gm) * I_DIM + col] = f2bf(s * uv);
        }
      }
    }
#undef GU_COMPUTE
}

// ---------------- Down GEMM + weighted scatter to out ----------------------------------
// R10 base (nt-fastest) + 2-deep prefetch. 512 thr, tile 128x128, BK=32,
// 8 waves (2Mx4N), acc = 8 f32x4, (512,4).
__global__ __launch_bounds__(512, 4) void down_kernel(const ushort_t* __restrict__ act,
                                                      const float* __restrict__ Wd,
                                                      const int* __restrict__ offsets,
                                                      const int* __restrict__ token_of,
                                                      const float* __restrict__ weight_of,
                                                      float* __restrict__ out) {
  int bid = xcd_swizzle(blockIdx.x, N_EXP * MT * 16);
  int e = bid / (MT * 16);
  int mt = (bid % (MT * 16)) / 16;  // nt fastest (R10 ordering)
  int nt = bid % 16;
  int base = offsets[e];
  int Me = offsets[e + 1] - base;
  if (mt * 128 >= Me) return;

  __shared__ ushort_t As[128 * LSTR];   // 10 KB
  __shared__ ushort_t Bs[128 * LSTR];   // 10 KB
  __shared__ int stok[128];
  __shared__ float sw[128];

  int tid = threadIdx.x;
  if (tid < 128) {
    int gm = mt * 128 + tid;
    int ok = gm < Me;
    int cm = ok ? gm : (Me - 1);
    stok[tid] = token_of[base + cm];
    sw[tid] = ok ? weight_of[base + gm] : 0.f;
  }
  __syncthreads();

  int wave = tid >> 6, lane = tid & 63;
  int wm = wave >> 2, wn = wave & 3;

  int sr = tid >> 2;
  int ac = (tid & 3) * 8;     // bf16 col (16 B / thread)
  int r0 = mt * 128 + sr;
  if (r0 >= Me) r0 = Me - 1;
  const ushort_t* pA = act + (size_t)(base + r0) * I_DIM + ac;
  int bc = (tid & 3) * 8;     // fp32 col (8 floats / thread)
  const float* pB = Wd + ((size_t)e * H_DIM + nt * 128 + sr) * I_DIM + bc;

  f32x4 acc[4][2];
#pragma unroll
  for (int i = 0; i < 4; ++i)
#pragma unroll
    for (int j = 0; j < 2; ++j) acc[i][j] = (f32x4)0.f;

  s16x8 rA0, rA1;
  float4 rB0[2], rB1[2];
  rA0 = *(const s16x8*)pA;
  rA1 = *(const s16x8*)(pA + 32);
#pragma unroll
  for (int j = 0; j < 2; ++j) {
    rB0[j] = *(const float4*)(pB + 4 * j);
    rB1[j] = *(const float4*)(pB + 32 + 4 * j);
  }

  int fr = lane & 15, q2 = lane >> 4;
  const int NK = I_DIM / 32;  // 32 (even)

#define DN_COMPUTE()                                                                \
  {                                                                                 \
    s16x8 af[4], bf[2];                                                             \
    _Pragma("unroll")                                                               \
    for (int mf = 0; mf < 4; ++mf)                                                  \
      af[mf] = *(const s16x8*)&As[(wm * 64 + mf * 16 + fr) * LSTR + q2 * 8];        \
    _Pragma("unroll")                                                               \
    for (int nf = 0; nf < 2; ++nf)                                                  \
      bf[nf] = *(const s16x8*)&Bs[(wn * 32 + nf * 16 + fr) * LSTR + q2 * 8];        \
    __builtin_amdgcn_s_setprio(1);                                                  \
    _Pragma("unroll")                                                               \
    for (int mf = 0; mf < 4; ++mf)                                                  \
      _Pragma("unroll")                                                             \
      for (int nf = 0; nf < 2; ++nf)                                                \
        acc[mf][nf] = mfma_bf16(af[mf], bf[nf], acc[mf][nf]);                       \
    __builtin_amdgcn_s_setprio(0);                                                  \
  }

  for (int k = 0; k < NK; k += 2) {
    BAR_RAW();
    *(s16x8*)&As[sr * LSTR + ac] = rA0;
    *(uint2*)&Bs[sr * LSTR + bc] = pk4(rB0[0]);
    *(uint2*)&Bs[sr * LSTR + bc + 4] = pk4(rB0[1]);
    if (k + 2 < NK) {
      int kn = (k + 2) * 32;
      rA0 = *(const s16x8*)(pA + kn);
#pragma unroll
      for (int j = 0; j < 2; ++j) rB0[j] = *(const float4*)(pB + kn + 4 * j);
    }
    BAR_LGKM();
    DN_COMPUTE();

    BAR_RAW();
    *(s16x8*)&As[sr * LSTR + ac] = rA1;
    *(uint2*)&Bs[sr * LSTR + bc] = pk4(rB1[0]);
    *(uint2*)&Bs[sr * LSTR + bc + 4] = pk4(rB1[1]);
    if (k + 3 < NK) {
      int kn = (k + 3) * 32;
      rA1 = *(const s16x8*)(pA + kn);
#pragma unroll
      for (int j = 0; j < 2; ++j) rB1[j] = *(const float4*)(pB + kn + 4 * j);
    }
    BAR_LGKM();
    DN_COMPUTE();
  }

#pragma unroll
  for (int mf = 0; mf < 4; ++mf)
#pragma unroll
    for (int nf = 0; nf < 2; ++nf) {
      f32x4 v = acc[mf][nf];
#pragma unroll
      for (int r = 0; r < 4; ++r) {
        int mloc = wm * 64 + mf * 16 + q2 * 4 + r;
        int gm = mt * 128 + mloc;
        if (gm < Me) {
          int t = stok[mloc];
          float w = sw[mloc];
          int h = nt * 128 + wn * 32 + nf * 16 + fr;
          unsafeAtomicAdd(&out[(size_t)t * H_DIM + h], w * v[r]);
        }
      }
    }
#undef DN_COMPUTE
}

// ---------------------------------------------------------------------------------------
extern "C" void kernel_launch(void* const* d_in, const int* in_sizes, int n_in,
                              void* d_out, int out_size, void* d_ws, size_t ws_size,
                              hipStream_t stream) {
  const float* X = (const float*)d_in[0];
  const float* GW = (const float*)d_in[1];
  const float* Wg = (const float*)d_in[2];
  const float* Wu = (const float*)d_in[3];
  const float* Wd = (const float*)d_in[4];
  float* out = (float*)d_out;
  float* logits = out + (size_t)T_TOK * H_DIM;

  char* ws = (char*)d_ws;
  int* counts = (int*)ws;                       // 256 B
  int* cursor = (int*)(ws + 256);               // 256 B
  int* offsets = (int*)(ws + 512);              // 260 B
  int* sel_e = (int*)(ws + 1024);               // 64 KB
  float* sel_w = (float*)(ws + 1024 + 65536);   // 64 KB
  int* token_of = (int*)(ws + 1024 + 2 * 65536);
  float* weight_of = (float*)(ws + 1024 + 3 * 65536);
  ushort_t* act = (ushort_t*)(ws + 524288);     // 16384*1024*2 = 32 MB

  hipMemsetAsync(out, 0, (size_t)T_TOK * H_DIM * sizeof(float), stream);
  hipMemsetAsync(ws, 0, 1024, stream);

  router_kernel<<<T_TOK / 4, 256, 0, stream>>>(X, GW, logits);
  topk_kernel<<<T_TOK / 4, 256, 0, stream>>>(logits, counts, sel_e, sel_w);
  scan_kernel<<<1, 64, 0, stream>>>(counts, offsets, cursor);
  assign_kernel<<<(T_TOK * TOPK) / 256, 256, 0, stream>>>(sel_e, sel_w, offsets, cursor,
                                                          token_of, weight_of);
  gateup_kernel<<<N_EXP * MT * 8, 512, 0, stream>>>(X, Wg, Wu, offsets, token_of, act);
  down_kernel<<<N_EXP * MT * 16, 512, 0, stream>>>(act, Wd, offsets, token_of,
                                                   weight_of, out);
}

// Round 17
// 819.433 us; speedup vs baseline: 1.1128x; 1.0212x over previous
//
#include <hip/hip_runtime.h>

typedef unsigned short ushort_t;
typedef unsigned int uint_t;

typedef __attribute__((ext_vector_type(8))) __bf16 bf16x8_t;
typedef __attribute__((ext_vector_type(8))) short s16x8;
typedef __attribute__((ext_vector_type(4))) float f32x4;

#define T_TOK 2048
#define H_DIM 2048
#define I_DIM 1024
#define N_EXP 64
#define TOPK 8
#define MTG 3        // 256-row m-tiles (gateup/down): covers up to 768 tokens/expert
#define LSTR 40      // LDS row stride in bf16 elems (BK=32 + 8 pad) — R4-proven

// Raw barrier: does NOT drain vmcnt -> in-flight global loads stay outstanding.
#define BAR_RAW()  asm volatile("s_barrier" ::: "memory")
// LDS-visibility barrier: drain ds ops (lgkm) then barrier; vmcnt untouched.
#define BAR_LGKM() asm volatile("s_waitcnt lgkmcnt(0)\n\ts_barrier" ::: "memory")

__device__ inline f32x4 mfma_bf16(s16x8 a, s16x8 b, f32x4 c) {
  return __builtin_amdgcn_mfma_f32_16x16x32_bf16(
      __builtin_bit_cast(bf16x8_t, a), __builtin_bit_cast(bf16x8_t, b), c, 0, 0, 0);
}

__device__ inline ushort_t f2bf(float f) {
  uint_t u = __float_as_uint(f);
  u += 0x7FFFu + ((u >> 16) & 1u);   // round-to-nearest-even
  return (ushort_t)(u >> 16);
}

// packed f32x2 -> bf16x2 (RNE), 1 instruction
__device__ inline uint_t pkbf(float a, float b) {
  uint_t r;
  asm("v_cvt_pk_bf16_f32 %0, %1, %2" : "=v"(r) : "v"(a), "v"(b));
  return r;
}
// float4 -> 4 bf16 (8 B)
__device__ inline uint2 pk4(float4 v) {
  uint2 w;
  w.x = pkbf(v.x, v.y);
  w.y = pkbf(v.z, v.w);
  return w;
}

// XCD-chunk swizzle (bijective when nwg % 8 == 0)
__device__ __forceinline__ int xcd_swizzle(int bid, int nwg) {
  int q = nwg >> 3;
  return (bid & 7) * q + (bid >> 3);
}

// ---------------- Router: logits[t][e] = sum_h x[t][h] * gw[e][h] (fp32 exact) ----------
__global__ __launch_bounds__(256) void router_kernel(const float* __restrict__ X,
                                                     const float* __restrict__ GW,
                                                     float* __restrict__ logits) {
  __shared__ float xs[4][H_DIM];
  int tid = threadIdx.x;
  int t0 = blockIdx.x * 4;
  const float4* src = (const float4*)(X + (size_t)t0 * H_DIM);
  float4* dst = (float4*)(&xs[0][0]);
#pragma unroll
  for (int j = 0; j < 8; ++j) dst[tid + 256 * j] = src[tid + 256 * j];
  __syncthreads();
  int wave = tid >> 6, lane = tid & 63;
  int t = t0 + wave;
  const float4* w = (const float4*)(GW + (size_t)lane * H_DIM);
  const float4* xr = (const float4*)(&xs[wave][0]);
  float acc = 0.f;
  for (int i = 0; i < H_DIM / 4; ++i) {
    float4 a = xr[i];
    float4 b = w[i];
    acc = fmaf(a.x, b.x, acc);
    acc = fmaf(a.y, b.y, acc);
    acc = fmaf(a.z, b.z, acc);
    acc = fmaf(a.w, b.w, acc);
  }
  logits[(size_t)t * N_EXP + lane] = acc;
}

// ---------------- Softmax + top-8 per token (one wave per token) -----------------------
__global__ __launch_bounds__(256) void topk_kernel(const float* __restrict__ logits,
                                                   int* __restrict__ counts,
                                                   int* __restrict__ sel_e,
                                                   float* __restrict__ sel_w) {
  int tid = threadIdx.x;
  int wave = tid >> 6, lane = tid & 63;
  int t = blockIdx.x * 4 + wave;
  float l = logits[(size_t)t * N_EXP + lane];
  float m = l;
#pragma unroll
  for (int s = 32; s; s >>= 1) m = fmaxf(m, __shfl_xor(m, s, 64));
  float p = __expf(l - m);
  float sum = p;
#pragma unroll
  for (int s = 32; s; s >>= 1) sum += __shfl_xor(sum, s, 64);
  float prob = p / sum;

  float val = l;
#pragma unroll
  for (int k = 0; k < TOPK; ++k) {
    float bv = val;
    int bi = lane;
#pragma unroll
    for (int s = 32; s; s >>= 1) {
      float ov = __shfl_xor(bv, s, 64);
      int oi = __shfl_xor(bi, s, 64);
      if (ov > bv || (ov == bv && oi < bi)) { bv = ov; bi = oi; }
    }
    float bw = __shfl(prob, bi, 64);
    if (lane == 0) {
      sel_e[t * TOPK + k] = bi;
      sel_w[t * TOPK + k] = bw;
      atomicAdd(&counts[bi], 1);
    }
    if (lane == bi) val = -INFINITY;
  }
}

// ---------------- Prefix sum over 64 expert counts -------------------------------------
__global__ void scan_kernel(const int* __restrict__ counts, int* __restrict__ offsets,
                            int* __restrict__ cursor) {
  if (threadIdx.x == 0) {
    int acc = 0;
    for (int e = 0; e < N_EXP; ++e) { offsets[e] = acc; acc += counts[e]; }
    offsets[N_EXP] = acc;
  }
  if (threadIdx.x < N_EXP) cursor[threadIdx.x] = 0;
}

// ---------------- Assign packed rows ---------------------------------------------------
__global__ __launch_bounds__(256) void assign_kernel(const int* __restrict__ sel_e,
                                                     const float* __restrict__ sel_w,
                                                     const int* __restrict__ offsets,
                                                     int* __restrict__ cursor,
                                                     int* __restrict__ token_of,
                                                     float* __restrict__ weight_of) {
  int idx = blockIdx.x * 256 + threadIdx.x;  // 0..16383
  int t = idx >> 3;
  int e = sel_e[idx];
  float w = sel_w[idx];
  int r = offsets[e] + atomicAdd(&cursor[e], 1);
  token_of[r] = t;
  weight_of[r] = w;
}

// ---------------- Fused gate+up GEMM + SiLU -> act (bf16), M=256 tile ------------------
// L2-demand attack: tile 256(M)x128(N) x2 proj, BK=32. 512 thr, 8 waves (2M x 4N),
// per-wave 128x32/proj -> acc = 32 f32x4 (128 AGPR). Each weight-panel byte now
// serves 2x the output rows -> L2 demand ~0.65x. 1-deep prefetch, 2-barrier
// schedule, nt-fastest + XCD swizzle (R10/R16-proven pieces).
__global__ __launch_bounds__(512, 2) void gateup_kernel(const float* __restrict__ X,
                                                        const float* __restrict__ Wg,
                                                        const float* __restrict__ Wu,
                                                        const int* __restrict__ offsets,
                                                        const int* __restrict__ token_of,
                                                        ushort_t* __restrict__ act) {
  int bid = xcd_swizzle(blockIdx.x, N_EXP * MTG * 8);
  int e = bid / (MTG * 8);
  int mt = (bid % (MTG * 8)) / 8;   // nt fastest
  int nt = bid % 8;
  int base = offsets[e];
  int Me = offsets[e + 1] - base;
  if (mt * 256 >= Me) return;

  __shared__ ushort_t As[256 * LSTR];   // 20 KB
  __shared__ ushort_t Bgs[128 * LSTR];  // 10 KB
  __shared__ ushort_t Bus[128 * LSTR];  // 10 KB
  __shared__ int stok[256];

  int tid = threadIdx.x;
  if (tid < 256) {
    int gm = mt * 256 + tid;
    int cm = gm < Me ? gm : (Me - 1);
    stok[tid] = token_of[base + cm];
  }
  __syncthreads();

  int wave = tid >> 6, lane = tid & 63;
  int wm = wave >> 2, wn = wave & 3;

  // A staging: 2 thr/row x 256 rows; each thread 16 floats (4 float4) at (tid&1)*16.
  int sa = tid >> 1, ca = (tid & 1) * 16;
  const float* pA = X + (size_t)stok[sa] * H_DIM + ca;
  // B staging: 4 thr/row x 128 rows; each thread 8 floats at (tid&3)*8.
  int sb = tid >> 2, cb = (tid & 3) * 8;
  const float* pG = Wg + ((size_t)e * I_DIM + nt * 128 + sb) * H_DIM + cb;
  const float* pU = Wu + ((size_t)e * I_DIM + nt * 128 + sb) * H_DIM + cb;

  f32x4 accg[8][2], accu[8][2];
#pragma unroll
  for (int i = 0; i < 8; ++i)
#pragma unroll
    for (int j = 0; j < 2; ++j) { accg[i][j] = (f32x4)0.f; accu[i][j] = (f32x4)0.f; }

  float4 rA[4], rG[2], rU[2];
#pragma unroll
  for (int j = 0; j < 4; ++j) rA[j] = *(const float4*)(pA + 4 * j);
#pragma unroll
  for (int j = 0; j < 2; ++j) {
    rG[j] = *(const float4*)(pG + 4 * j);
    rU[j] = *(const float4*)(pU + 4 * j);
  }

  int fr = lane & 15, q2 = lane >> 4;

  for (int k0 = 0; k0 < H_DIM; k0 += 32) {
    BAR_RAW();  // all waves done reading prev tile; prefetch loads cross freely
#pragma unroll
    for (int j = 0; j < 4; ++j)
      *(uint2*)&As[sa * LSTR + ca + 4 * j] = pk4(rA[j]);
    *(uint2*)&Bgs[sb * LSTR + cb] = pk4(rG[0]);
    *(uint2*)&Bgs[sb * LSTR + cb + 4] = pk4(rG[1]);
    *(uint2*)&Bus[sb * LSTR + cb] = pk4(rU[0]);
    *(uint2*)&Bus[sb * LSTR + cb + 4] = pk4(rU[1]);
    if (k0 + 32 < H_DIM) {
      int kn = k0 + 32;
#pragma unroll
      for (int j = 0; j < 4; ++j) rA[j] = *(const float4*)(pA + kn + 4 * j);
#pragma unroll
      for (int j = 0; j < 2; ++j) {
        rG[j] = *(const float4*)(pG + kn + 4 * j);
        rU[j] = *(const float4*)(pU + kn + 4 * j);
      }
    }
    BAR_LGKM();  // ds_writes visible; vmcnt untouched (prefetch in flight)

    s16x8 bg[2], bu[2];
#pragma unroll
    for (int nf = 0; nf < 2; ++nf) {
      bg[nf] = *(const s16x8*)&Bgs[(wn * 32 + nf * 16 + fr) * LSTR + q2 * 8];
      bu[nf] = *(const s16x8*)&Bus[(wn * 32 + nf * 16 + fr) * LSTR + q2 * 8];
    }
    __builtin_amdgcn_s_setprio(1);
#pragma unroll
    for (int mf = 0; mf < 8; ++mf) {
      s16x8 af = *(const s16x8*)&As[(wm * 128 + mf * 16 + fr) * LSTR + q2 * 8];
#pragma unroll
      for (int nf = 0; nf < 2; ++nf) {
        accg[mf][nf] = mfma_bf16(af, bg[nf], accg[mf][nf]);
        accu[mf][nf] = mfma_bf16(af, bu[nf], accu[mf][nf]);
      }
    }
    __builtin_amdgcn_s_setprio(0);
  }

  // epilogue: act = silu(g)*u -> bf16
#pragma unroll
  for (int mf = 0; mf < 8; ++mf)
#pragma unroll
    for (int nf = 0; nf < 2; ++nf) {
      f32x4 g = accg[mf][nf], u = accu[mf][nf];
#pragma unroll
      for (int r = 0; r < 4; ++r) {
        int mloc = wm * 128 + mf * 16 + q2 * 4 + r;
        int gm = mt * 256 + mloc;
        if (gm < Me) {
          float gv = g[r], uv = u[r];
          float s = gv / (1.f + __expf(-gv));
          int col = nt * 128 + wn * 32 + nf * 16 + fr;
          act[(size_t)(base + gm) * I_DIM + col] = f2bf(s * uv);
        }
      }
    }
}

// ---------------- Down GEMM + weighted scatter to out, M=256 tile ----------------------
// tile 256(M)x128(N), BK=32, 512 thr, 8 waves (2M x 4N), per-wave 128x32 ->
// acc = 16 f32x4 (64 AGPR). (512,3). L2 demand ~0.65x vs M=128.
__global__ __launch_bounds__(512, 3) void down_kernel(const ushort_t* __restrict__ act,
                                                      const float* __restrict__ Wd,
                                                      const int* __restrict__ offsets,
                                                      const int* __restrict__ token_of,
                                                      const float* __restrict__ weight_of,
                                                      float* __restrict__ out) {
  int bid = xcd_swizzle(blockIdx.x, N_EXP * MTG * 16);
  int e = bid / (MTG * 16);
  int mt = (bid % (MTG * 16)) / 16;  // nt fastest
  int nt = bid % 16;
  int base = offsets[e];
  int Me = offsets[e + 1] - base;
  if (mt * 256 >= Me) return;

  __shared__ ushort_t As[256 * LSTR];   // 20 KB
  __shared__ ushort_t Bs[128 * LSTR];   // 10 KB
  __shared__ int stok[256];
  __shared__ float sw[256];

  int tid = threadIdx.x;
  if (tid < 256) {
    int gm = mt * 256 + tid;
    int ok = gm < Me;
    int cm = ok ? gm : (Me - 1);
    stok[tid] = token_of[base + cm];
    sw[tid] = ok ? weight_of[base + gm] : 0.f;
  }
  __syncthreads();

  int wave = tid >> 6, lane = tid & 63;
  int wm = wave >> 2, wn = wave & 3;

  // A (act, bf16): 2 thr/row x 256 rows; 16 bf16 (32 B = 2 s16x8) at (tid&1)*16.
  int sa = tid >> 1;
  int ca = (tid & 1) * 16;
  int r0 = mt * 256 + sa;
  if (r0 >= Me) r0 = Me - 1;
  const ushort_t* pA = act + (size_t)(base + r0) * I_DIM + ca;
  // B (Wd, fp32): 4 thr/row x 128 rows; 8 floats at (tid&3)*8.
  int sb = tid >> 2, cb = (tid & 3) * 8;
  const float* pB = Wd + ((size_t)e * H_DIM + nt * 128 + sb) * I_DIM + cb;

  f32x4 acc[8][2];
#pragma unroll
  for (int i = 0; i < 8; ++i)
#pragma unroll
    for (int j = 0; j < 2; ++j) acc[i][j] = (f32x4)0.f;

  s16x8 rA[2];
  float4 rB[2];
  rA[0] = *(const s16x8*)pA;
  rA[1] = *(const s16x8*)(pA + 8);
#pragma unroll
  for (int j = 0; j < 2; ++j) rB[j] = *(const float4*)(pB + 4 * j);

  int fr = lane & 15, q2 = lane >> 4;

  for (int k0 = 0; k0 < I_DIM; k0 += 32) {
    BAR_RAW();
    *(s16x8*)&As[sa * LSTR + ca] = rA[0];
    *(s16x8*)&As[sa * LSTR + ca + 8] = rA[1];
    *(uint2*)&Bs[sb * LSTR + cb] = pk4(rB[0]);
    *(uint2*)&Bs[sb * LSTR + cb + 4] = pk4(rB[1]);
    if (k0 + 32 < I_DIM) {
      int kn = k0 + 32;
      rA[0] = *(const s16x8*)(pA + kn);
      rA[1] = *(const s16x8*)(pA + kn + 8);
#pragma unroll
      for (int j = 0; j < 2; ++j) rB[j] = *(const float4*)(pB + kn + 4 * j);
    }
    BAR_LGKM();

    s16x8 bf[2];
#pragma unroll
    for (int nf = 0; nf < 2; ++nf)
      bf[nf] = *(const s16x8*)&Bs[(wn * 32 + nf * 16 + fr) * LSTR + q2 * 8];
    __builtin_amdgcn_s_setprio(1);
#pragma unroll
    for (int mf = 0; mf < 8; ++mf) {
      s16x8 af = *(const s16x8*)&As[(wm * 128 + mf * 16 + fr) * LSTR + q2 * 8];
#pragma unroll
      for (int nf = 0; nf < 2; ++nf)
        acc[mf][nf] = mfma_bf16(af, bf[nf], acc[mf][nf]);
    }
    __builtin_amdgcn_s_setprio(0);
  }

#pragma unroll
  for (int mf = 0; mf < 8; ++mf)
#pragma unroll
    for (int nf = 0; nf < 2; ++nf) {
      f32x4 v = acc[mf][nf];
#pragma unroll
      for (int r = 0; r < 4; ++r) {
        int mloc = wm * 128 + mf * 16 + q2 * 4 + r;
        int gm = mt * 256 + mloc;
        if (gm < Me) {
          int t = stok[mloc];
          float w = sw[mloc];
          int h = nt * 128 + wn * 32 + nf * 16 + fr;
          unsafeAtomicAdd(&out[(size_t)t * H_DIM + h], w * v[r]);
        }
      }
    }
}

// ---------------------------------------------------------------------------------------
extern "C" void kernel_launch(void* const* d_in, const int* in_sizes, int n_in,
                              void* d_out, int out_size, void* d_ws, size_t ws_size,
                              hipStream_t stream) {
  const float* X = (const float*)d_in[0];
  const float* GW = (const float*)d_in[1];
  const float* Wg = (const float*)d_in[2];
  const float* Wu = (const float*)d_in[3];
  const float* Wd = (const float*)d_in[4];
  float* out = (float*)d_out;
  float* logits = out + (size_t)T_TOK * H_DIM;

  char* ws = (char*)d_ws;
  int* counts = (int*)ws;                       // 256 B
  int* cursor = (int*)(ws + 256);               // 256 B
  int* offsets = (int*)(ws + 512);              // 260 B
  int* sel_e = (int*)(ws + 1024);               // 64 KB
  float* sel_w = (float*)(ws + 1024 + 65536);   // 64 KB
  int* token_of = (int*)(ws + 1024 + 2 * 65536);
  float* weight_of = (float*)(ws + 1024 + 3 * 65536);
  ushort_t* act = (ushort_t*)(ws + 524288);     // 16384*1024*2 = 32 MB

  hipMemsetAsync(out, 0, (size_t)T_TOK * H_DIM * sizeof(float), stream);
  hipMemsetAsync(ws, 0, 1024, stream);

  router_kernel<<<T_TOK / 4, 256, 0, stream>>>(X, GW, logits);
  topk_kernel<<<T_TOK / 4, 256, 0, stream>>>(logits, counts, sel_e, sel_w);
  scan_kernel<<<1, 64, 0, stream>>>(counts, offsets, cursor);
  assign_kernel<<<(T_TOK * TOPK) / 256, 256, 0, stream>>>(sel_e, sel_w, offsets, cursor,
                                                          token_of, weight_of);
  gateup_kernel<<<N_EXP * MTG * 8, 512, 0, stream>>>(X, Wg, Wu, offsets, token_of, act);
  down_kernel<<<N_EXP * MTG * 16, 512, 0, stream>>>(act, Wd, offsets, token_of,
                                                    weight_of, out);
}

// Round 18
// 810.242 us; speedup vs baseline: 1.1254x; 1.0113x over previous
//
#include <hip/hip_runtime.h>

typedef unsigned short ushort_t;
typedef unsigned int uint_t;

typedef __attribute__((ext_vector_type(8))) __bf16 bf16x8_t;
typedef __attribute__((ext_vector_type(8))) short s16x8;
typedef __attribute__((ext_vector_type(4))) float f32x4;

#define T_TOK 2048
#define H_DIM 2048
#define I_DIM 1024
#define N_EXP 64
#define TOPK 8
#define MT 6         // gateup: 128-row m-tiles (covers 768 tokens/expert)
#define MTG 3        // down: 256-row m-tiles
#define LSTR 40      // LDS row stride in bf16 elems (BK=32 + 8 pad)

// Raw barrier: does NOT drain vmcnt -> in-flight global loads stay outstanding.
#define BAR_RAW()  asm volatile("s_barrier" ::: "memory")
// LDS-visibility barrier: drain ds ops (lgkm) then barrier; vmcnt untouched.
#define BAR_LGKM() asm volatile("s_waitcnt lgkmcnt(0)\n\ts_barrier" ::: "memory")

__device__ inline f32x4 mfma_bf16(s16x8 a, s16x8 b, f32x4 c) {
  return __builtin_amdgcn_mfma_f32_16x16x32_bf16(
      __builtin_bit_cast(bf16x8_t, a), __builtin_bit_cast(bf16x8_t, b), c, 0, 0, 0);
}

__device__ inline ushort_t f2bf(float f) {
  uint_t u = __float_as_uint(f);
  u += 0x7FFFu + ((u >> 16) & 1u);   // round-to-nearest-even
  return (ushort_t)(u >> 16);
}

// packed f32x2 -> bf16x2 (RNE), 1 instruction
__device__ inline uint_t pkbf(float a, float b) {
  uint_t r;
  asm("v_cvt_pk_bf16_f32 %0, %1, %2" : "=v"(r) : "v"(a), "v"(b));
  return r;
}
// float4 -> 4 bf16 (8 B)
__device__ inline uint2 pk4(float4 v) {
  uint2 w;
  w.x = pkbf(v.x, v.y);
  w.y = pkbf(v.z, v.w);
  return w;
}

// XCD-chunk swizzle (bijective when nwg % 8 == 0)
__device__ __forceinline__ int xcd_swizzle(int bid, int nwg) {
  int q = nwg >> 3;
  return (bid & 7) * q + (bid >> 3);
}

// ---------------- Router: logits[t][e] = sum_h x[t][h] * gw[e][h] (fp32 exact) ----------
__global__ __launch_bounds__(256) void router_kernel(const float* __restrict__ X,
                                                     const float* __restrict__ GW,
                                                     float* __restrict__ logits) {
  __shared__ float xs[4][H_DIM];
  int tid = threadIdx.x;
  int t0 = blockIdx.x * 4;
  const float4* src = (const float4*)(X + (size_t)t0 * H_DIM);
  float4* dst = (float4*)(&xs[0][0]);
#pragma unroll
  for (int j = 0; j < 8; ++j) dst[tid + 256 * j] = src[tid + 256 * j];
  __syncthreads();
  int wave = tid >> 6, lane = tid & 63;
  int t = t0 + wave;
  const float4* w = (const float4*)(GW + (size_t)lane * H_DIM);
  const float4* xr = (const float4*)(&xs[wave][0]);
  float acc = 0.f;
  for (int i = 0; i < H_DIM / 4; ++i) {
    float4 a = xr[i];
    float4 b = w[i];
    acc = fmaf(a.x, b.x, acc);
    acc = fmaf(a.y, b.y, acc);
    acc = fmaf(a.z, b.z, acc);
    acc = fmaf(a.w, b.w, acc);
  }
  logits[(size_t)t * N_EXP + lane] = acc;
}

// ---------------- Softmax + top-8 per token (one wave per token) -----------------------
__global__ __launch_bounds__(256) void topk_kernel(const float* __restrict__ logits,
                                                   int* __restrict__ counts,
                                                   int* __restrict__ sel_e,
                                                   float* __restrict__ sel_w) {
  int tid = threadIdx.x;
  int wave = tid >> 6, lane = tid & 63;
  int t = blockIdx.x * 4 + wave;
  float l = logits[(size_t)t * N_EXP + lane];
  float m = l;
#pragma unroll
  for (int s = 32; s; s >>= 1) m = fmaxf(m, __shfl_xor(m, s, 64));
  float p = __expf(l - m);
  float sum = p;
#pragma unroll
  for (int s = 32; s; s >>= 1) sum += __shfl_xor(sum, s, 64);
  float prob = p / sum;

  float val = l;
#pragma unroll
  for (int k = 0; k < TOPK; ++k) {
    float bv = val;
    int bi = lane;
#pragma unroll
    for (int s = 32; s; s >>= 1) {
      float ov = __shfl_xor(bv, s, 64);
      int oi = __shfl_xor(bi, s, 64);
      if (ov > bv || (ov == bv && oi < bi)) { bv = ov; bi = oi; }
    }
    float bw = __shfl(prob, bi, 64);
    if (lane == 0) {
      sel_e[t * TOPK + k] = bi;
      sel_w[t * TOPK + k] = bw;
      atomicAdd(&counts[bi], 1);
    }
    if (lane == bi) val = -INFINITY;
  }
}

// ---------------- Prefix sum over 64 expert counts -------------------------------------
__global__ void scan_kernel(const int* __restrict__ counts, int* __restrict__ offsets,
                            int* __restrict__ cursor) {
  if (threadIdx.x == 0) {
    int acc = 0;
    for (int e = 0; e < N_EXP; ++e) { offsets[e] = acc; acc += counts[e]; }
    offsets[N_EXP] = acc;
  }
  if (threadIdx.x < N_EXP) cursor[threadIdx.x] = 0;
}

// ---------------- Assign packed rows ---------------------------------------------------
__global__ __launch_bounds__(256) void assign_kernel(const int* __restrict__ sel_e,
                                                     const float* __restrict__ sel_w,
                                                     const int* __restrict__ offsets,
                                                     int* __restrict__ cursor,
                                                     int* __restrict__ token_of,
                                                     float* __restrict__ weight_of) {
  int idx = blockIdx.x * 256 + threadIdx.x;  // 0..16383
  int t = idx >> 3;
  int e = sel_e[idx];
  float w = sel_w[idx];
  int r = offsets[e] + atomicAdd(&cursor[e], 1);
  token_of[r] = t;
  weight_of[r] = w;
}

// ---------------- Fused gate+up GEMM + SiLU -> act (bf16) — R16 exact ------------------
// 512 thr, tile 128(M)x128(N) x2 proj, BK=32, 8 waves (2M x 4N), wave 64x32/proj
// (acc = 16 f32x4), 2-deep register prefetch, (512,3), nt-fastest + XCD swizzle.
// Measured best gateup of the series: 408 us.
__global__ __launch_bounds__(512, 3) void gateup_kernel(const float* __restrict__ X,
                                                        const float* __restrict__ Wg,
                                                        const float* __restrict__ Wu,
                                                        const int* __restrict__ offsets,
                                                        const int* __restrict__ token_of,
                                                        ushort_t* __restrict__ act) {
  int bid = xcd_swizzle(blockIdx.x, N_EXP * MT * 8);
  int e = bid / (MT * 8);
  int mt = (bid % (MT * 8)) / 8;   // nt fastest
  int nt = bid % 8;
  int base = offsets[e];
  int Me = offsets[e + 1] - base;
  if (mt * 128 >= Me) return;

  __shared__ ushort_t As[128 * LSTR];   // 10 KB
  __shared__ ushort_t Bgs[128 * LSTR];  // 10 KB
  __shared__ ushort_t Bus[128 * LSTR];  // 10 KB
  __shared__ int stok[128];

  int tid = threadIdx.x;
  if (tid < 128) {
    int gm = mt * 128 + tid;
    int cm = gm < Me ? gm : (Me - 1);
    stok[tid] = token_of[base + cm];
  }
  __syncthreads();

  int wave = tid >> 6, lane = tid & 63;
  int wm = wave >> 2, wn = wave & 3;

  int sr = tid >> 2, sc = (tid & 3) * 8;
  const float* pA = X + (size_t)stok[sr] * H_DIM + sc;
  const float* pG = Wg + ((size_t)e * I_DIM + nt * 128 + sr) * H_DIM + sc;
  const float* pU = Wu + ((size_t)e * I_DIM + nt * 128 + sr) * H_DIM + sc;

  f32x4 accg[4][2], accu[4][2];
#pragma unroll
  for (int i = 0; i < 4; ++i)
#pragma unroll
    for (int j = 0; j < 2; ++j) { accg[i][j] = (f32x4)0.f; accu[i][j] = (f32x4)0.f; }

  // 2-deep prefetch: set0 = even tiles, set1 = odd tiles
  float4 a0[2], g0[2], u0[2], a1[2], g1[2], u1[2];
#pragma unroll
  for (int j = 0; j < 2; ++j) {
    a0[j] = *(const float4*)(pA + 4 * j);
    g0[j] = *(const float4*)(pG + 4 * j);
    u0[j] = *(const float4*)(pU + 4 * j);
    a1[j] = *(const float4*)(pA + 32 + 4 * j);
    g1[j] = *(const float4*)(pG + 32 + 4 * j);
    u1[j] = *(const float4*)(pU + 32 + 4 * j);
  }

  int fr = lane & 15, q2 = lane >> 4;
  const int NK = H_DIM / 32;  // 64 (even)

#define GU_COMPUTE()                                                                \
  {                                                                                 \
    s16x8 af[4], bg[2], bu[2];                                                      \
    _Pragma("unroll")                                                               \
    for (int mf = 0; mf < 4; ++mf)                                                  \
      af[mf] = *(const s16x8*)&As[(wm * 64 + mf * 16 + fr) * LSTR + q2 * 8];        \
    _Pragma("unroll")                                                               \
    for (int nf = 0; nf < 2; ++nf) {                                                \
      bg[nf] = *(const s16x8*)&Bgs[(wn * 32 + nf * 16 + fr) * LSTR + q2 * 8];       \
      bu[nf] = *(const s16x8*)&Bus[(wn * 32 + nf * 16 + fr) * LSTR + q2 * 8];       \
    }                                                                               \
    __builtin_amdgcn_s_setprio(1);                                                  \
    _Pragma("unroll")                                                               \
    for (int mf = 0; mf < 4; ++mf)                                                  \
      _Pragma("unroll")                                                             \
      for (int nf = 0; nf < 2; ++nf) {                                              \
        accg[mf][nf] = mfma_bf16(af[mf], bg[nf], accg[mf][nf]);                     \
        accu[mf][nf] = mfma_bf16(af[mf], bu[nf], accu[mf][nf]);                     \
      }                                                                             \
    __builtin_amdgcn_s_setprio(0);                                                  \
  }

  for (int k = 0; k < NK; k += 2) {
    // even tile k (set0): ds_write's vmcnt wait targets loads issued at k-2
    BAR_RAW();
    *(uint2*)&As[sr * LSTR + sc] = pk4(a0[0]);
    *(uint2*)&As[sr * LSTR + sc + 4] = pk4(a0[1]);
    *(uint2*)&Bgs[sr * LSTR + sc] = pk4(g0[0]);
    *(uint2*)&Bgs[sr * LSTR + sc + 4] = pk4(g0[1]);
    *(uint2*)&Bus[sr * LSTR + sc] = pk4(u0[0]);
    *(uint2*)&Bus[sr * LSTR + sc + 4] = pk4(u0[1]);
    if (k + 2 < NK) {
      int kn = (k + 2) * 32;
#pragma unroll
      for (int j = 0; j < 2; ++j) {
        a0[j] = *(const float4*)(pA + kn + 4 * j);
        g0[j] = *(const float4*)(pG + kn + 4 * j);
        u0[j] = *(const float4*)(pU + kn + 4 * j);
      }
    }
    BAR_LGKM();
    GU_COMPUTE();

    // odd tile k+1 (set1)
    BAR_RAW();
    *(uint2*)&As[sr * LSTR + sc] = pk4(a1[0]);
    *(uint2*)&As[sr * LSTR + sc + 4] = pk4(a1[1]);
    *(uint2*)&Bgs[sr * LSTR + sc] = pk4(g1[0]);
    *(uint2*)&Bgs[sr * LSTR + sc + 4] = pk4(g1[1]);
    *(uint2*)&Bus[sr * LSTR + sc] = pk4(u1[0]);
    *(uint2*)&Bus[sr * LSTR + sc + 4] = pk4(u1[1]);
    if (k + 3 < NK) {
      int kn = (k + 3) * 32;
#pragma unroll
      for (int j = 0; j < 2; ++j) {
        a1[j] = *(const float4*)(pA + kn + 4 * j);
        g1[j] = *(const float4*)(pG + kn + 4 * j);
        u1[j] = *(const float4*)(pU + kn + 4 * j);
      }
    }
    BAR_LGKM();
    GU_COMPUTE();
  }

  // epilogue: act = silu(g)*u -> bf16
#pragma unroll
  for (int mf = 0; mf < 4; ++mf)
#pragma unroll
    for (int nf = 0; nf < 2; ++nf) {
      f32x4 g = accg[mf][nf], u = accu[mf][nf];
#pragma unroll
      for (int r = 0; r < 4; ++r) {
        int mloc = wm * 64 + mf * 16 + q2 * 4 + r;
        int gm = mt * 128 + mloc;
        if (gm < Me) {
          float gv = g[r], uv = u[r];
          float s = gv / (1.f + __expf(-gv));
          int col = nt * 128 + wn * 32 + nf * 16 + fr;
          act[(size_t)(base + gm) * I_DIM + col] = f2bf(s * uv);
        }
      }
    }
#undef GU_COMPUTE
}

// ---------------- Down GEMM + weighted scatter to out — R17 exact ----------------------
// tile 256(M)x128(N), BK=32, 512 thr, 8 waves (2M x 4N), per-wave 128x32 ->
// acc = 16 f32x4 (64 AGPR). (512,3), 1-deep prefetch. Measured best down: ~143 us.
__global__ __launch_bounds__(512, 3) void down_kernel(const ushort_t* __restrict__ act,
                                                      const float* __restrict__ Wd,
                                                      const int* __restrict__ offsets,
                                                      const int* __restrict__ token_of,
                                                      const float* __restrict__ weight_of,
                                                      float* __restrict__ out) {
  int bid = xcd_swizzle(blockIdx.x, N_EXP * MTG * 16);
  int e = bid / (MTG * 16);
  int mt = (bid % (MTG * 16)) / 16;  // nt fastest
  int nt = bid % 16;
  int base = offsets[e];
  int Me = offsets[e + 1] - base;
  if (mt * 256 >= Me) return;

  __shared__ ushort_t As[256 * LSTR];   // 20 KB
  __shared__ ushort_t Bs[128 * LSTR];   // 10 KB
  __shared__ int stok[256];
  __shared__ float sw[256];

  int tid = threadIdx.x;
  if (tid < 256) {
    int gm = mt * 256 + tid;
    int ok = gm < Me;
    int cm = ok ? gm : (Me - 1);
    stok[tid] = token_of[base + cm];
    sw[tid] = ok ? weight_of[base + gm] : 0.f;
  }
  __syncthreads();

  int wave = tid >> 6, lane = tid & 63;
  int wm = wave >> 2, wn = wave & 3;

  // A (act, bf16): 2 thr/row x 256 rows; 16 bf16 (32 B = 2 s16x8) at (tid&1)*16.
  int sa = tid >> 1;
  int ca = (tid & 1) * 16;
  int r0 = mt * 256 + sa;
  if (r0 >= Me) r0 = Me - 1;
  const ushort_t* pA = act + (size_t)(base + r0) * I_DIM + ca;
  // B (Wd, fp32): 4 thr/row x 128 rows; 8 floats at (tid&3)*8.
  int sb = tid >> 2, cb = (tid & 3) * 8;
  const float* pB = Wd + ((size_t)e * H_DIM + nt * 128 + sb) * I_DIM + cb;

  f32x4 acc[8][2];
#pragma unroll
  for (int i = 0; i < 8; ++i)
#pragma unroll
    for (int j = 0; j < 2; ++j) acc[i][j] = (f32x4)0.f;

  s16x8 rA[2];
  float4 rB[2];
  rA[0] = *(const s16x8*)pA;
  rA[1] = *(const s16x8*)(pA + 8);
#pragma unroll
  for (int j = 0; j < 2; ++j) rB[j] = *(const float4*)(pB + 4 * j);

  int fr = lane & 15, q2 = lane >> 4;

  for (int k0 = 0; k0 < I_DIM; k0 += 32) {
    BAR_RAW();
    *(s16x8*)&As[sa * LSTR + ca] = rA[0];
    *(s16x8*)&As[sa * LSTR + ca + 8] = rA[1];
    *(uint2*)&Bs[sb * LSTR + cb] = pk4(rB[0]);
    *(uint2*)&Bs[sb * LSTR + cb + 4] = pk4(rB[1]);
    if (k0 + 32 < I_DIM) {
      int kn = k0 + 32;
      rA[0] = *(const s16x8*)(pA + kn);
      rA[1] = *(const s16x8*)(pA + kn + 8);
#pragma unroll
      for (int j = 0; j < 2; ++j) rB[j] = *(const float4*)(pB + kn + 4 * j);
    }
    BAR_LGKM();

    s16x8 bf[2];
#pragma unroll
    for (int nf = 0; nf < 2; ++nf)
      bf[nf] = *(const s16x8*)&Bs[(wn * 32 + nf * 16 + fr) * LSTR + q2 * 8];
    __builtin_amdgcn_s_setprio(1);
#pragma unroll
    for (int mf = 0; mf < 8; ++mf) {
      s16x8 af = *(const s16x8*)&As[(wm * 128 + mf * 16 + fr) * LSTR + q2 * 8];
#pragma unroll
      for (int nf = 0; nf < 2; ++nf)
        acc[mf][nf] = mfma_bf16(af, bf[nf], acc[mf][nf]);
    }
    __builtin_amdgcn_s_setprio(0);
  }

#pragma unroll
  for (int mf = 0; mf < 8; ++mf)
#pragma unroll
    for (int nf = 0; nf < 2; ++nf) {
      f32x4 v = acc[mf][nf];
#pragma unroll
      for (int r = 0; r < 4; ++r) {
        int mloc = wm * 128 + mf * 16 + q2 * 4 + r;
        int gm = mt * 256 + mloc;
        if (gm < Me) {
          int t = stok[mloc];
          float w = sw[mloc];
          int h = nt * 128 + wn * 32 + nf * 16 + fr;
          unsafeAtomicAdd(&out[(size_t)t * H_DIM + h], w * v[r]);
        }
      }
    }
}

// ---------------------------------------------------------------------------------------
extern "C" void kernel_launch(void* const* d_in, const int* in_sizes, int n_in,
                              void* d_out, int out_size, void* d_ws, size_t ws_size,
                              hipStream_t stream) {
  const float* X = (const float*)d_in[0];
  const float* GW = (const float*)d_in[1];
  const float* Wg = (const float*)d_in[2];
  const float* Wu = (const float*)d_in[3];
  const float* Wd = (const float*)d_in[4];
  float* out = (float*)d_out;
  float* logits = out + (size_t)T_TOK * H_DIM;

  char* ws = (char*)d_ws;
  int* counts = (int*)ws;                       // 256 B
  int* cursor = (int*)(ws + 256);               // 256 B
  int* offsets = (int*)(ws + 512);              // 260 B
  int* sel_e = (int*)(ws + 1024);               // 64 KB
  float* sel_w = (float*)(ws + 1024 + 65536);   // 64 KB
  int* token_of = (int*)(ws + 1024 + 2 * 65536);
  float* weight_of = (float*)(ws + 1024 + 3 * 65536);
  ushort_t* act = (ushort_t*)(ws + 524288);     // 16384*1024*2 = 32 MB

  hipMemsetAsync(out, 0, (size_t)T_TOK * H_DIM * sizeof(float), stream);
  hipMemsetAsync(ws, 0, 1024, stream);

  router_kernel<<<T_TOK / 4, 256, 0, stream>>>(X, GW, logits);
  topk_kernel<<<T_TOK / 4, 256, 0, stream>>>(logits, counts, sel_e, sel_w);
  scan_kernel<<<1, 64, 0, stream>>>(counts, offsets, cursor);
  assign_kernel<<<(T_TOK * TOPK) / 256, 256, 0, stream>>>(sel_e, sel_w, offsets, cursor,
                                                          token_of, weight_of);
  gateup_kernel<<<N_EXP * MT * 8, 512, 0, stream>>>(X, Wg, Wu, offsets, token_of, act);
  down_kernel<<<N_EXP * MTG * 16, 512, 0, stream>>>(act, Wd, offsets, token_of,
                                                    weight_of, out);
}